// Round 3
// baseline (838.312 us; speedup 1.0000x reference)
//
#include <hip/hip_runtime.h>
#include <hip/hip_bf16.h>
#include <cstdint>
#include <cstddef>

#define F 128       // feature dim
#define BSH 8       // rows per bucket = 256
#define MAXB 512    // max buckets supported (N <= 131072)
#define CHSH 13     // col-chunk = 8192 rows = 2 MB bf16 x-slice (fits 4 MB XCD L2)
#define NCH_MAX 15
typedef __attribute__((ext_vector_type(8))) short short8;
typedef __attribute__((ext_vector_type(4))) float floatx4;

static __device__ inline float bf2f(unsigned u) {            // u = bf16 in low 16
    return __builtin_bit_cast(float, u << 16);
}
static __device__ inline unsigned short f2bf(float f) {
    return __builtin_bit_cast(unsigned short, __float2bfloat16(f));
}
static __device__ inline unsigned pack2(float a, float b) {  // low = a, high = b
    return ((unsigned)f2bf(b) << 16) | (unsigned)f2bf(a);
}

// 8-wide bf16 FMA into fp32 accumulator
static __device__ inline void fma8(float* A, float v, uint4 q) {
    A[0] += v * bf2f(q.x & 0xffffu); A[1] += v * bf2f(q.x >> 16);
    A[2] += v * bf2f(q.y & 0xffffu); A[3] += v * bf2f(q.y >> 16);
    A[4] += v * bf2f(q.z & 0xffffu); A[5] += v * bf2f(q.z >> 16);
    A[6] += v * bf2f(q.w & 0xffffu); A[7] += v * bf2f(q.w >> 16);
}

// ---------------------------------------------------------------------------
// cast x (fp32) -> plane0 (bf16). thread = 4 elements.
// ---------------------------------------------------------------------------
__global__ __launch_bounds__(256) void cast_x(
    const float4* __restrict__ x, uint2* __restrict__ p0, long long n4)
{
    long long i = (long long)blockIdx.x * 256 + threadIdx.x;
    if (i < n4) {
        float4 v = x[i];
        p0[i] = make_uint2(pack2(v.x, v.y), pack2(v.z, v.w));
    }
}

// ---------------------------------------------------------------------------
// W [128][512] fp32, W[o][f*4+j]  ->  Wp [128][512] bf16, Wp[o][j*128+f]
// ---------------------------------------------------------------------------
__global__ __launch_bounds__(256) void perm_w(
    const float* __restrict__ W, unsigned short* __restrict__ Wp)
{
    int t = blockIdx.x * 256 + threadIdx.x;   // 65536 total
    int o = t >> 9, rem = t & 511;
    int j = rem >> 7, f = rem & 127;
    Wp[t] = f2bf(W[(size_t)o * 512 + f * 4 + j]);
}

// ---------------------------------------------------------------------------
// Counting-sort pass 0: per-bucket edge totals (LDS-aggregated flush)
// ---------------------------------------------------------------------------
__global__ __launch_bounds__(256) void coarse_hist(
    const int* __restrict__ rows, int* __restrict__ bucketTot, int nE, int nb)
{
    __shared__ int h[MAXB];
    for (int i = threadIdx.x; i < MAXB; i += 256) h[i] = 0;
    __syncthreads();
    int stride = gridDim.x * 256;
    for (int e = blockIdx.x * 256 + threadIdx.x; e < nE; e += stride)
        atomicAdd(&h[rows[e] >> BSH], 1);
    __syncthreads();
    for (int i = threadIdx.x; i < nb; i += 256)
        if (h[i]) atomicAdd(&bucketTot[i], h[i]);
}

// ---------------------------------------------------------------------------
// Counting-sort pass 0b: exclusive scan of bucket totals (single block)
// ---------------------------------------------------------------------------
__global__ __launch_bounds__(512) void bucket_scan(
    const int* __restrict__ tot, int* __restrict__ bucketStart,
    int* __restrict__ bucketCur, int nb)
{
    int t = threadIdx.x;
    int orig = (t < nb) ? tot[t] : 0;
    int v = orig;
    int lane = t & 63, wave = t >> 6;
#pragma unroll
    for (int d = 1; d < 64; d <<= 1) {
        int u = __shfl_up(v, d);
        if (lane >= d) v += u;
    }
    __shared__ int ws[8];
    if (lane == 63) ws[wave] = v;
    __syncthreads();
    int add = 0;
    for (int w = 0; w < wave; w++) add += ws[w];
    int excl = v + add - orig;
    if (t < nb) { bucketStart[t] = excl; bucketCur[t] = excl; }
}

// ---------------------------------------------------------------------------
// Counting-sort pass 1: bucket-scatter with per-block LDS histogram + rank.
// ---------------------------------------------------------------------------
__global__ __launch_bounds__(256) void pass1_scatter(
    const int* __restrict__ rows, const int* __restrict__ cols,
    const float* __restrict__ vals, int* __restrict__ bucketCur,
    uint2* __restrict__ tmp, int nE, int nb)
{
    __shared__ int hcnt[MAXB];
    __shared__ int hbase[MAXB];
    int chunk = (nE + gridDim.x - 1) / gridDim.x;
    int e0 = blockIdx.x * chunk;
    int e1 = min(e0 + chunk, nE);

    for (int i = threadIdx.x; i < MAXB; i += 256) hcnt[i] = 0;
    __syncthreads();
    for (int e = e0 + threadIdx.x; e < e1; e += 256)
        atomicAdd(&hcnt[rows[e] >> BSH], 1);
    __syncthreads();
    for (int i = threadIdx.x; i < nb; i += 256) {
        int c = hcnt[i];
        hbase[i] = c ? atomicAdd(&bucketCur[i], c) : 0;
        hcnt[i] = 0;                          // reuse as rank cursor
    }
    __syncthreads();
    for (int e = e0 + threadIdx.x; e < e1; e += 256) {  // chunk re-read is L2-hot
        int r = rows[e];
        int b = r >> BSH;
        int k = atomicAdd(&hcnt[b], 1);
        tmp[hbase[b] + k] = make_uint2(
            ((unsigned)(r & ((1 << BSH) - 1)) << 17) | (unsigned)cols[e],
            __float_as_uint(vals[e]));
    }
}

// ---------------------------------------------------------------------------
// Counting-sort pass 2: one block per bucket, key = (row_low, col_chunk).
// Emits edges sorted by (row, chunk) + flat boundary array rcp[n*nch+1]:
//   segment (r,c) = [rcp[r*nch+c], rcp[r*nch+c+1]); chains across rows.
// ---------------------------------------------------------------------------
__global__ __launch_bounds__(256) void pass2_finalize(
    const uint2* __restrict__ tmp, const int* __restrict__ bucketStart,
    const int* __restrict__ bucketCur, int* __restrict__ rcp,
    int2* __restrict__ edges, int n, int nch)
{
    int b = blockIdx.x;
    int base = bucketStart[b], end = bucketCur[b];  // cur==end after pass1
    int r0 = b << BSH;
    int t = threadIdx.x;

    __shared__ int cnt[256 * (NCH_MAX + 1)];        // 16 KB
    for (int i = t; i < 256 * nch; i += 256) cnt[i] = 0;
    __syncthreads();
    for (int i = base + t; i < end; i += 256) {
        unsigned rx = tmp[i].x;
        int cc = (int)((rx & 0x1FFFFu) >> CHSH);
        if (cc >= nch) cc = nch - 1;                // safety clamp
        atomicAdd(&cnt[(int)(rx >> 17) * nch + cc], 1);
    }
    __syncthreads();

    // thread t owns row r0+t: its nch chunk counts are cnt[t*nch .. t*nch+nch)
    int local[NCH_MAX + 1];
    int sum = 0;
#pragma unroll
    for (int c = 0; c < NCH_MAX + 1; c++) {         // static indices (no scratch)
        int v = (c < nch) ? cnt[t * nch + c] : 0;
        local[c] = v; sum += v;
    }
    int v = sum;
    int lane = t & 63, wave = t >> 6;
#pragma unroll
    for (int d = 1; d < 64; d <<= 1) {
        int u = __shfl_up(v, d);
        if (lane >= d) v += u;
    }
    __shared__ int ws[4];
    if (lane == 63) ws[wave] = v;
    __syncthreads();
    int add = 0;
    for (int w = 0; w < wave; w++) add += ws[w];
    int run = base + v + add - sum;                 // row start (exclusive prefix)

    int r = r0 + t;
    if (r < n) {
#pragma unroll
        for (int c = 0; c < NCH_MAX + 1; c++) {
            if (c < nch) {
                rcp[(size_t)r * nch + c] = run;
                cnt[t * nch + c] = run;             // reuse as placement cursor
                run += local[c];
            }
        }
        if (r == n - 1) rcp[(size_t)n * nch] = run; // global sentinel = E
    }
    __syncthreads();
    for (int i = base + t; i < end; i += 256) {
        uint2 rec = tmp[i];
        int cc = (int)((rec.x & 0x1FFFFu) >> CHSH);
        if (cc >= nch) cc = nch - 1;
        int p = atomicAdd(&cnt[(int)(rec.x >> 17) * nch + cc], 1);
        edges[p] = make_int2((int)(rec.x & 0x1FFFF), (int)rec.y);
    }
}

// ---------------------------------------------------------------------------
// Chunk-swept gather SpMM v3: uniform pipelined j-iteration.
// Wave owns 16 rows as 4 sets of 4; within a set, the wave's four 16-lane
// groups each take ONE row and run a single wave-uniform loop to
// max(segment len) (2x shfl_xor reduce -> scalar loop). Per iteration:
// prefetch next edge rec, issue current gather, masked FMA. No divergent
// while-loops, no per-segment branches; rec->gather chain broken by 1-iter
// prefetch. Grid = ceil(N/64) is fully co-resident (7 blocks/CU at <=73 VGPR)
// so all blocks sweep chunks in near-lockstep -> x-slice stays L2-resident.
// ---------------------------------------------------------------------------
__global__ __launch_bounds__(256, 7) void spmm_bf16(
    const int* __restrict__ rcp, const int2* __restrict__ edges,
    const unsigned short* __restrict__ xb, const unsigned short* __restrict__ prevb,
    unsigned short* __restrict__ yb, float scale, float beta, int n, int nch)
{
    int wid = (blockIdx.x * 256 + threadIdx.x) >> 6;   // global wave id
    int lane = threadIdx.x & 63;
    int g = lane >> 4, l = lane & 15;
    int rowBase = wid * 16;                            // wave owns 16 rows
    if (rowBase >= n) return;

    const char* xb8 = (const char*)xb;
    unsigned loff = (unsigned)(l * 16);                // byte offset within x-row

    float acc[4][8];
#pragma unroll
    for (int s = 0; s < 4; s++)
#pragma unroll
        for (int j = 0; j < 8; j++) acc[s][j] = 0.f;

    // bounds preload: for set s, lane (g,l) holds rcp[row(s,g)*nch + min(l,nch)]
    int bnd[4];
    int ll = l <= nch ? l : nch;
#pragma unroll
    for (int s = 0; s < 4; s++) {
        int row = rowBase + s * 4 + g;
        if (row > n - 1) row = n - 1;
        bnd[s] = rcp[(size_t)row * nch + ll];
    }

    for (int c = 0; c < nch; c++) {
        int srcBase = (lane & 48);                     // group's lane base
#pragma unroll
        for (int s = 0; s < 4; s++) {
            int sE = __shfl(bnd[s], srcBase | c, 64);
            int eE = __shfl(bnd[s], srcBase | (c + 1), 64);
            int len = eE - sE;
            int m1 = max(len, __shfl_xor(len, 16));
            int mx = max(m1, __shfl_xor(m1, 32));      // wave-uniform

            if (mx > 0) {
                int2 recA = edges[(0 < len) ? sE : 0];
                for (int j = 0; j < mx; j++) {
                    int2 recB = edges[(j + 1 < len) ? sE + j + 1 : 0];  // prefetch
                    uint4 w = *(const uint4*)(xb8 + ((((unsigned)recA.x) << 8) | loff));
                    float v = (j < len) ? __int_as_float(recA.y) : 0.f;
                    fma8(acc[s], v, w);
                    recA = recB;
                }
            }
        }
    }

#pragma unroll
    for (int s = 0; s < 4; s++) {
        int row = rowBase + s * 4 + g;
        if (row < n) {
            float o8[8];
#pragma unroll
            for (int j = 0; j < 8; j++) o8[j] = scale * acc[s][j];
            if (beta != 0.f) {
                uint4 p = *(const uint4*)(prevb + (size_t)row * F + l * 8);
                o8[0] += beta * bf2f(p.x & 0xffffu); o8[1] += beta * bf2f(p.x >> 16);
                o8[2] += beta * bf2f(p.y & 0xffffu); o8[3] += beta * bf2f(p.y >> 16);
                o8[4] += beta * bf2f(p.z & 0xffffu); o8[5] += beta * bf2f(p.z >> 16);
                o8[6] += beta * bf2f(p.w & 0xffffu); o8[7] += beta * bf2f(p.w >> 16);
            }
            uint4 o;
            o.x = pack2(o8[0], o8[1]); o.y = pack2(o8[2], o8[3]);
            o.z = pack2(o8[4], o8[5]); o.w = pack2(o8[6], o8[7]);
            *(uint4*)(yb + (size_t)row * F + l * 8) = o;
        }
    }
}

// ---------------------------------------------------------------------------
// out[N,128] = cheb[N,512](bf16 planes) @ Wp^T + bias, MFMA 16x16x32.
// Register-resident B: wave w owns col-tiles nt={2w,2w+1}, preloads its 32
// B-frags (128 VGPRs) ONCE, then grid-strides over 16-row M-tiles doing
// 16 A-loads + 32 MFMAs + 8 stores per tile.
// ---------------------------------------------------------------------------
__global__ __launch_bounds__(256) void gemm_mfma(
    const unsigned short* __restrict__ Tb, const unsigned short* __restrict__ Wp,
    const float* __restrict__ bias, float* __restrict__ out, int n, int nTiles)
{
    int wave = threadIdx.x >> 6, lane = threadIdx.x & 63;
    int l15 = lane & 15, quad = lane >> 4;
    size_t planeStride = (size_t)n * F;

    // preload B fragments for this wave's two col-tiles
    short8 bfr[2][16];
    float bv[2];
#pragma unroll
    for (int nt = 0; nt < 2; nt++) {
        int col = (wave * 2 + nt) * 16 + l15;
        bv[nt] = bias[col];
        const unsigned short* bp = Wp + ((size_t)col << 9) + quad * 8;
#pragma unroll
        for (int kk = 0; kk < 16; kk++)
            bfr[nt][kk] = __builtin_bit_cast(short8, *(const uint4*)(bp + kk * 32));
    }

    for (int tile = blockIdx.x; tile < nTiles; tile += gridDim.x) {
        int m0 = tile * 16;
        int m = m0 + l15;
        int mc = m < n ? m : n - 1;

        short8 a[16];
#pragma unroll
        for (int kk = 0; kk < 16; kk++) {
            const unsigned short* ap = Tb + (size_t)(kk >> 2) * planeStride
                                     + (size_t)mc * F + (kk & 3) * 32 + quad * 8;
            a[kk] = __builtin_bit_cast(short8, *(const uint4*)ap);
        }

        floatx4 acc[2];
        acc[0] = (floatx4){0.f, 0.f, 0.f, 0.f};
        acc[1] = (floatx4){0.f, 0.f, 0.f, 0.f};
#pragma unroll
        for (int kk = 0; kk < 16; kk++) {
            acc[0] = __builtin_amdgcn_mfma_f32_16x16x32_bf16(a[kk], bfr[0][kk], acc[0], 0, 0, 0);
            acc[1] = __builtin_amdgcn_mfma_f32_16x16x32_bf16(a[kk], bfr[1][kk], acc[1], 0, 0, 0);
        }

#pragma unroll
        for (int nt = 0; nt < 2; nt++) {
            int ncol = (wave * 2 + nt) * 16 + l15;
#pragma unroll
            for (int r = 0; r < 4; r++) {
                int mrow = m0 + quad * 4 + r;
                if (mrow < n) out[(size_t)mrow * F + ncol] = acc[nt][r] + bv[nt];
            }
        }
    }
}

extern "C" void kernel_launch(void* const* d_in, const int* in_sizes, int n_in,
                              void* d_out, int out_size, void* d_ws, size_t ws_size,
                              hipStream_t stream)
{
    const float* x    = (const float*)d_in[0];
    const int*   rows = (const int*)d_in[1];
    const int*   cols = (const int*)d_in[2];
    const float* vals = (const float*)d_in[3];
    const float* W    = (const float*)d_in[4];
    const float* bias = (const float*)d_in[5];

    int N = in_sizes[0] / F;
    int E = in_sizes[1];
    int NB = (N + (1 << BSH) - 1) >> BSH;       // buckets (391 for N=100k)
    int NCH = (N + ((1 << CHSH) - 1)) >> CHSH;  // col chunks (13 for N=100k)
    if (NCH > NCH_MAX) NCH = NCH_MAX;
    float* out = (float*)d_out;

    // ---- workspace layout ----
    size_t planeElems = (size_t)N * F;                       // bf16 elems
    unsigned short* P0 = (unsigned short*)d_ws;              // 25.6 MB each
    unsigned short* P1 = P0 + planeElems;
    unsigned short* P2 = P1 + planeElems;
    unsigned short* P3 = P2 + planeElems;
    int2* edges = (int2*)(P3 + planeElems);                  // 25.6 MB
    unsigned short* Wp = (unsigned short*)(edges + E);       // 128 KB
    int* bucketTot   = (int*)(Wp + 128 * 512);               // MAXB
    int* bucketStart = bucketTot + MAXB;                     // MAXB
    int* bucketCur   = bucketStart + MAXB;                   // MAXB
    int* rcp         = bucketCur + MAXB;                     // N*NCH+1 (5.2 MB)
    uint2* tmp = (uint2*)P2;   // 25.6 MB staging, consumed before P2 written

    long long n4 = planeElems / 4;
    int castBlocks = (int)((n4 + 255) / 256);

    // ---- independent prep ----
    cast_x<<<castBlocks, 256, 0, stream>>>((const float4*)x, (uint2*)P0, n4);
    perm_w<<<256, 256, 0, stream>>>(W, Wp);

    // ---- CSR build: 2-pass counting sort, keys (row, col-chunk) ----
    hipMemsetAsync(bucketTot, 0, MAXB * sizeof(int), stream);
    coarse_hist<<<256, 256, 0, stream>>>(rows, bucketTot, E, NB);
    bucket_scan<<<1, 512, 0, stream>>>(bucketTot, bucketStart, bucketCur, NB);
    pass1_scatter<<<512, 256, 0, stream>>>(rows, cols, vals, bucketCur, tmp, E, NB);
    pass2_finalize<<<NB, 256, 0, stream>>>(tmp, bucketStart, bucketCur,
                                           rcp, edges, N, NCH);

    // ---- Chebyshev recurrence (chunk-swept SpMM) ----
    int spmmBlocks = (N + 63) / 64;
    spmm_bf16<<<spmmBlocks, 256, 0, stream>>>(rcp, edges, P0, nullptr, P1, 1.0f,  0.0f, N, NCH);
    spmm_bf16<<<spmmBlocks, 256, 0, stream>>>(rcp, edges, P1, P0,      P2, 2.0f, -1.0f, N, NCH);
    spmm_bf16<<<spmmBlocks, 256, 0, stream>>>(rcp, edges, P2, P1,      P3, 2.0f, -1.0f, N, NCH);

    // ---- fused projection: out = cheb @ Wp^T + b ----
    int nTiles = (N + 15) / 16;
    int gemmGrid = nTiles < 1536 ? nTiles : 1536;
    gemm_mfma<<<gemmGrid, 256, 0, stream>>>(P0, Wp, bias, out, N, nTiles);
}

// Round 4
// 641.181 us; speedup vs baseline: 1.3074x; 1.3074x over previous
//
#include <hip/hip_runtime.h>
#include <hip/hip_bf16.h>
#include <cstdint>
#include <cstddef>

#define F 128       // feature dim
#define BSH 8       // rows per bucket = 256
#define MAXB 512    // max buckets supported (N <= 131072)
#define P1CHUNK 6272 // max edges per pass1 block cached in LDS (grid 512, E=3.2M -> 6250)
typedef __attribute__((ext_vector_type(8))) short short8;
typedef __attribute__((ext_vector_type(4))) float floatx4;

static __device__ inline float bf2f(unsigned u) {            // u = bf16 in low 16
    return __builtin_bit_cast(float, u << 16);
}
static __device__ inline unsigned short f2bf(float f) {
    return __builtin_bit_cast(unsigned short, __float2bfloat16(f));
}
static __device__ inline unsigned pack2(float a, float b) {  // low = a, high = b
    return ((unsigned)f2bf(b) << 16) | (unsigned)f2bf(a);
}

// ---------------------------------------------------------------------------
// Fused prep: blocks [0,castBlocks) cast x fp32->bf16 plane0 (4 elem/thread);
// blocks [castBlocks, castBlocks+256) permute W; the rest (1024) histogram
// rows into bucketTot. All three are independent; fusing removes 2 dispatch
// boundaries. bucketTot is pre-zeroed by hipMemsetAsync before this kernel.
// ---------------------------------------------------------------------------
__global__ __launch_bounds__(256) void prep_fused(
    const float4* __restrict__ x, uint2* __restrict__ p0, long long n4,
    const float* __restrict__ W, unsigned short* __restrict__ Wp,
    const int* __restrict__ rows, int* __restrict__ bucketTot, int nE, int nb,
    int castBlocks, int histBlocks)
{
    int b = blockIdx.x;
    if (b < castBlocks) {
        long long i = (long long)b * 256 + threadIdx.x;
        if (i < n4) {
            float4 v = x[i];
            p0[i] = make_uint2(pack2(v.x, v.y), pack2(v.z, v.w));
        }
        return;
    }
    b -= castBlocks;
    if (b < 256) {
        // W [128][512] fp32, W[o][f*4+j] -> Wp [128][512] bf16, Wp[o][j*128+f]
        int t = b * 256 + threadIdx.x;   // 65536 total
        int o = t >> 9, rem = t & 511;
        int j = rem >> 7, f = rem & 127;
        Wp[t] = f2bf(W[(size_t)o * 512 + f * 4 + j]);
        return;
    }
    b -= 256;
    // histogram: histBlocks blocks, grid-stride over edges, LDS-aggregated
    __shared__ int h[MAXB];
    for (int i = threadIdx.x; i < MAXB; i += 256) h[i] = 0;
    __syncthreads();
    int stride = histBlocks * 256;
    for (int e = b * 256 + threadIdx.x; e < nE; e += stride)
        atomicAdd(&h[rows[e] >> BSH], 1);
    __syncthreads();
    for (int i = threadIdx.x; i < nb; i += 256)
        if (h[i]) atomicAdd(&bucketTot[i], h[i]);
}

// ---------------------------------------------------------------------------
// Counting-sort pass 0b: exclusive scan of bucket totals (single block)
// ---------------------------------------------------------------------------
__global__ __launch_bounds__(512) void bucket_scan(
    const int* __restrict__ tot, int* __restrict__ bucketStart,
    int* __restrict__ bucketCur, int nb)
{
    int t = threadIdx.x;
    int orig = (t < nb) ? tot[t] : 0;
    int v = orig;
    int lane = t & 63, wave = t >> 6;
#pragma unroll
    for (int d = 1; d < 64; d <<= 1) {
        int u = __shfl_up(v, d);
        if (lane >= d) v += u;
    }
    __shared__ int ws[8];
    if (lane == 63) ws[wave] = v;
    __syncthreads();
    int add = 0;
    for (int w = 0; w < wave; w++) add += ws[w];
    int excl = v + add - orig;
    if (t < nb) { bucketStart[t] = excl; bucketCur[t] = excl; }
}

// ---------------------------------------------------------------------------
// Counting-sort pass 1: bucket-scatter with per-block LDS histogram + rank.
// Row ids for the block's chunk are cached in LDS during the histogram pass
// so the scatter pass does not re-read rows[] from global (saves 12.8 MB).
// ---------------------------------------------------------------------------
__global__ __launch_bounds__(256) void pass1_scatter(
    const int* __restrict__ rows, const int* __restrict__ cols,
    const float* __restrict__ vals, int* __restrict__ bucketCur,
    uint2* __restrict__ tmp, int nE, int nb)
{
    __shared__ int hcnt[MAXB];
    __shared__ int hbase[MAXB];
    __shared__ int rcache[P1CHUNK];
    int chunk = (nE + gridDim.x - 1) / gridDim.x;
    int e0 = blockIdx.x * chunk;
    int e1 = min(e0 + chunk, nE);
    bool cache = (e1 - e0) <= P1CHUNK;

    for (int i = threadIdx.x; i < MAXB; i += 256) hcnt[i] = 0;
    __syncthreads();
    for (int e = e0 + threadIdx.x; e < e1; e += 256) {
        int r = rows[e];
        if (cache) rcache[e - e0] = r;
        atomicAdd(&hcnt[r >> BSH], 1);
    }
    __syncthreads();
    for (int i = threadIdx.x; i < nb; i += 256) {
        int c = hcnt[i];
        hbase[i] = c ? atomicAdd(&bucketCur[i], c) : 0;
        hcnt[i] = 0;                          // reuse as rank cursor
    }
    __syncthreads();
    for (int e = e0 + threadIdx.x; e < e1; e += 256) {
        int r = cache ? rcache[e - e0] : rows[e];
        int b = r >> BSH;
        int k = atomicAdd(&hcnt[b], 1);
        tmp[hbase[b] + k] = make_uint2(
            ((unsigned)(r & ((1 << BSH) - 1)) << 17) | (unsigned)cols[e],
            __float_as_uint(vals[e]));
    }
}

// ---------------------------------------------------------------------------
// Counting-sort pass 2: one block per bucket -> rowStart/rowEnd + final edges
// ---------------------------------------------------------------------------
__global__ __launch_bounds__(256) void pass2_finalize(
    const uint2* __restrict__ tmp, const int* __restrict__ bucketStart,
    const int* __restrict__ bucketCur, int* __restrict__ rowStart,
    int* __restrict__ rowEnd, int2* __restrict__ edges, int n)
{
    int b = blockIdx.x;
    int base = bucketStart[b], end = bucketCur[b];  // cur==end after pass1
    int r0 = b << BSH;
    int t = threadIdx.x;

    __shared__ int cnt[1 << BSH];
    cnt[t] = 0;
    __syncthreads();
    for (int i = base + t; i < end; i += 256)
        atomicAdd(&cnt[tmp[i].x >> 17], 1);
    __syncthreads();

    int orig = cnt[t];
    int v = orig;
    int lane = t & 63, wave = t >> 6;
#pragma unroll
    for (int d = 1; d < 64; d <<= 1) {
        int u = __shfl_up(v, d);
        if (lane >= d) v += u;
    }
    __shared__ int ws[4];
    if (lane == 63) ws[wave] = v;
    __syncthreads();
    int add = 0;
    for (int w = 0; w < wave; w++) add += ws[w];
    int offs = base + v + add - orig;               // exclusive prefix + base

    int r = r0 + t;
    if (r < n) { rowStart[r] = offs; rowEnd[r] = offs + orig; }
    cnt[t] = offs;                                  // reuse as placement cursor
    __syncthreads();
    for (int i = base + t; i < end; i += 256) {
        uint2 rec = tmp[i];
        int rl = rec.x >> 17;
        int p = atomicAdd(&cnt[rl], 1);
        edges[p] = make_int2((int)(rec.x & 0x1FFFF), (int)rec.y);
    }
}

// ---------------------------------------------------------------------------
// bf16 gather SpMM + fused Chebyshev epilogue (round-0 proven structure:
// wave per row, 4 groups x 4-deep unroll = 16 gathers in flight)
// ---------------------------------------------------------------------------
__global__ __launch_bounds__(256) void spmm_bf16(
    const int* __restrict__ rowStart, const int* __restrict__ rowEnd,
    const int2* __restrict__ edges, const unsigned short* __restrict__ xb,
    const unsigned short* __restrict__ prevb, unsigned short* __restrict__ yb,
    float scale, float beta, int n)
{
    int row = blockIdx.x * 4 + (threadIdx.x >> 6);
    if (row >= n) return;
    int lane = threadIdx.x & 63;
    int g = lane >> 4, l = lane & 15;

    int s = rowStart[row];
    int c = rowEnd[row] - s;

    float acc[8];
#pragma unroll
    for (int j = 0; j < 8; j++) acc[j] = 0.f;

    for (int i = 0; i < c; i += 16) {
        uint4 w[4];
        float v[4];
#pragma unroll
        for (int u = 0; u < 4; u++) {
            int ii = i + u * 4 + g;
            bool ok = ii < c;
            int2 e = edges[s + (ok ? ii : 0)];
            w[u] = *(const uint4*)(xb + (size_t)e.x * F + l * 8);
            v[u] = ok ? __int_as_float(e.y) : 0.f;
        }
#pragma unroll
        for (int u = 0; u < 4; u++) {
            acc[0] += v[u] * bf2f(w[u].x & 0xffffu); acc[1] += v[u] * bf2f(w[u].x >> 16);
            acc[2] += v[u] * bf2f(w[u].y & 0xffffu); acc[3] += v[u] * bf2f(w[u].y >> 16);
            acc[4] += v[u] * bf2f(w[u].z & 0xffffu); acc[5] += v[u] * bf2f(w[u].z >> 16);
            acc[6] += v[u] * bf2f(w[u].w & 0xffffu); acc[7] += v[u] * bf2f(w[u].w >> 16);
        }
    }

#pragma unroll
    for (int j = 0; j < 8; j++) {
        acc[j] += __shfl_xor(acc[j], 16);
        acc[j] += __shfl_xor(acc[j], 32);
    }

    if (g == 0) {
        float r[8];
#pragma unroll
        for (int j = 0; j < 8; j++) r[j] = scale * acc[j];
        if (beta != 0.f) {
            uint4 p = *(const uint4*)(prevb + (size_t)row * F + l * 8);
            r[0] += beta * bf2f(p.x & 0xffffu); r[1] += beta * bf2f(p.x >> 16);
            r[2] += beta * bf2f(p.y & 0xffffu); r[3] += beta * bf2f(p.y >> 16);
            r[4] += beta * bf2f(p.z & 0xffffu); r[5] += beta * bf2f(p.z >> 16);
            r[6] += beta * bf2f(p.w & 0xffffu); r[7] += beta * bf2f(p.w >> 16);
        }
        uint4 o;
        o.x = pack2(r[0], r[1]); o.y = pack2(r[2], r[3]);
        o.z = pack2(r[4], r[5]); o.w = pack2(r[6], r[7]);
        *(uint4*)(yb + (size_t)row * F + l * 8) = o;
    }
}

// ---------------------------------------------------------------------------
// out[N,128] = cheb[N,512](bf16 planes) @ Wp^T + bias, MFMA 16x16x32.
// Register-resident B: wave w owns col-tiles nt={2w,2w+1}, preloads its 32
// B-frags (128 VGPRs) ONCE, then grid-strides over 16-row M-tiles doing
// 16 A-loads + 32 MFMAs + 8 stores per tile.
// ---------------------------------------------------------------------------
__global__ __launch_bounds__(256) void gemm_mfma(
    const unsigned short* __restrict__ Tb, const unsigned short* __restrict__ Wp,
    const float* __restrict__ bias, float* __restrict__ out, int n, int nTiles)
{
    int wave = threadIdx.x >> 6, lane = threadIdx.x & 63;
    int l15 = lane & 15, quad = lane >> 4;
    size_t planeStride = (size_t)n * F;

    // preload B fragments for this wave's two col-tiles
    short8 bfr[2][16];
    float bv[2];
#pragma unroll
    for (int nt = 0; nt < 2; nt++) {
        int col = (wave * 2 + nt) * 16 + l15;
        bv[nt] = bias[col];
        const unsigned short* bp = Wp + ((size_t)col << 9) + quad * 8;
#pragma unroll
        for (int kk = 0; kk < 16; kk++)
            bfr[nt][kk] = __builtin_bit_cast(short8, *(const uint4*)(bp + kk * 32));
    }

    for (int tile = blockIdx.x; tile < nTiles; tile += gridDim.x) {
        int m0 = tile * 16;
        int m = m0 + l15;
        int mc = m < n ? m : n - 1;

        short8 a[16];
#pragma unroll
        for (int kk = 0; kk < 16; kk++) {
            const unsigned short* ap = Tb + (size_t)(kk >> 2) * planeStride
                                     + (size_t)mc * F + (kk & 3) * 32 + quad * 8;
            a[kk] = __builtin_bit_cast(short8, *(const uint4*)ap);
        }

        floatx4 acc[2];
        acc[0] = (floatx4){0.f, 0.f, 0.f, 0.f};
        acc[1] = (floatx4){0.f, 0.f, 0.f, 0.f};
#pragma unroll
        for (int kk = 0; kk < 16; kk++) {
            acc[0] = __builtin_amdgcn_mfma_f32_16x16x32_bf16(a[kk], bfr[0][kk], acc[0], 0, 0, 0);
            acc[1] = __builtin_amdgcn_mfma_f32_16x16x32_bf16(a[kk], bfr[1][kk], acc[1], 0, 0, 0);
        }

#pragma unroll
        for (int nt = 0; nt < 2; nt++) {
            int ncol = (wave * 2 + nt) * 16 + l15;
#pragma unroll
            for (int r = 0; r < 4; r++) {
                int mrow = m0 + quad * 4 + r;
                if (mrow < n) out[(size_t)mrow * F + ncol] = acc[nt][r] + bv[nt];
            }
        }
    }
}

extern "C" void kernel_launch(void* const* d_in, const int* in_sizes, int n_in,
                              void* d_out, int out_size, void* d_ws, size_t ws_size,
                              hipStream_t stream)
{
    const float* x    = (const float*)d_in[0];
    const int*   rows = (const int*)d_in[1];
    const int*   cols = (const int*)d_in[2];
    const float* vals = (const float*)d_in[3];
    const float* W    = (const float*)d_in[4];
    const float* bias = (const float*)d_in[5];

    int N = in_sizes[0] / F;
    int E = in_sizes[1];
    int NB = (N + (1 << BSH) - 1) >> BSH;       // buckets (391 for N=100k)
    float* out = (float*)d_out;

    // ---- workspace layout ----
    size_t planeElems = (size_t)N * F;                       // bf16 elems
    unsigned short* P0 = (unsigned short*)d_ws;              // 25.6 MB each
    unsigned short* P1 = P0 + planeElems;
    unsigned short* P2 = P1 + planeElems;
    unsigned short* P3 = P2 + planeElems;
    int2* edges = (int2*)(P3 + planeElems);                  // 25.6 MB
    unsigned short* Wp = (unsigned short*)(edges + E);       // 128 KB
    int* bucketTot   = (int*)(Wp + 128 * 512);               // MAXB
    int* bucketStart = bucketTot + MAXB;                     // MAXB
    int* bucketCur   = bucketStart + MAXB;                   // MAXB
    int* rowStart    = bucketCur + MAXB;                     // N
    int* rowEnd      = rowStart + N;                         // N
    uint2* tmp = (uint2*)P2;   // 25.6 MB staging, consumed before P2 written

    long long n4 = planeElems / 4;
    int castBlocks = (int)((n4 + 255) / 256);
    int histBlocks = 1024;

    // ---- fused prep: cast_x | perm_w | coarse_hist ----
    hipMemsetAsync(bucketTot, 0, MAXB * sizeof(int), stream);
    prep_fused<<<castBlocks + 256 + histBlocks, 256, 0, stream>>>(
        (const float4*)x, (uint2*)P0, n4, W, Wp, rows, bucketTot, E, NB,
        castBlocks, histBlocks);

    // ---- CSR build: 2-pass counting sort, L2-resident scatter ----
    bucket_scan<<<1, 512, 0, stream>>>(bucketTot, bucketStart, bucketCur, NB);
    pass1_scatter<<<512, 256, 0, stream>>>(rows, cols, vals, bucketCur, tmp, E, NB);
    pass2_finalize<<<NB, 256, 0, stream>>>(tmp, bucketStart, bucketCur,
                                           rowStart, rowEnd, edges, N);

    // ---- Chebyshev recurrence ----
    int spmmBlocks = (N + 3) / 4;
    spmm_bf16<<<spmmBlocks, 256, 0, stream>>>(rowStart, rowEnd, edges, P0, nullptr, P1, 1.0f,  0.0f, N);
    spmm_bf16<<<spmmBlocks, 256, 0, stream>>>(rowStart, rowEnd, edges, P1, P0,      P2, 2.0f, -1.0f, N);
    spmm_bf16<<<spmmBlocks, 256, 0, stream>>>(rowStart, rowEnd, edges, P2, P1,      P3, 2.0f, -1.0f, N);

    // ---- fused projection: out = cheb @ Wp^T + b ----
    int nTiles = (N + 15) / 16;
    int gemmGrid = nTiles < 1536 ? nTiles : 1536;
    gemm_mfma<<<gemmGrid, 256, 0, stream>>>(P0, Wp, bias, out, N, nTiles);
}